// Round 15
// baseline (400.333 us; speedup 1.0000x reference)
//
#include <hip/hip_runtime.h>
#include <hip/hip_cooperative_groups.h>

namespace cg = cooperative_groups;

#define BB 2
#define CC 256
#define CQ 64
#define DD 32
#define HH 64
#define WW 192
#define HW (HH*WW)     // 12288
#define NPIX (BB*HW)   // 24576

typedef __attribute__((ext_vector_type(8))) short bf16x8;
typedef __attribute__((ext_vector_type(4))) float f32x4;

__device__ __forceinline__ float b2f(ushort s){ return __uint_as_float(((uint)s)<<16); }
__device__ __forceinline__ ushort f2b(float f){
    uint u = __float_as_uint(f);
    return (ushort)((u + 0x7fffu + ((u>>16)&1u)) >> 16);
}
__device__ __forceinline__ float eluf(float v){ return v > 0.f ? v : (__expf(v)-1.f); }

#define BANDC 96
#define STS2 20
#define PFS2 100

struct MArgs {
    const float *t_feat, *s_feat, *directs;
    const int   *img_w;
    const float *qw,*qb,*kw,*kb,*vw,*vb,*p1w,*p1b,*p2w,*p2b,*rw,*rb;
    ushort *Wqkv; float *bqkv; ushort *A1,*A2,*Ar;
    ushort *X1,*VbT,*X2; float *C1; ushort *Agg;
    float *cost_out, *xout;
};

// ==================== MEGA: all 5 stages, grid-synced ====================
__global__ __launch_bounds__(256, 5) void mega(MArgs a)
{
    __shared__ __align__(16) char smem[26112];
    cg::grid_group grid = cg::this_grid();
    int tid = threadIdx.x;
    int nb  = gridDim.x;

    // ---------- phase 0: weight prep ----------
    for (int id = blockIdx.x*256 + tid; id < 215232; id += nb*256){
        if (id < 49152) {
            int o = id / 256, c = id % 256;
            float v = (o<64)? a.qw[o*256+c] : (o<128)? a.kw[(o-64)*256+c] : a.vw[(o-128)*256+c];
            a.Wqkv[id] = f2b(v);
        } else if (id < 49344) {
            int o = id - 49152;
            a.bqkv[o] = (o<64)? a.qb[o] : (o<128)? a.kb[o-64] : a.vb[o-128];
        } else if (id < 49344+73728) {
            int i = id - 49344;
            int o = i/1152, r = i%1152, t = r/128, ci = r%128;
            a.A1[i] = f2b(a.p1w[(size_t)(o*128+ci)*9 + t]);
        } else if (id < 49344+73728+18432) {
            int i = id - (49344+73728);
            int o = i/576, r = i%576, t = r/64, ci = r%64;
            a.A2[i] = f2b(a.p2w[(size_t)(o*64+ci)*9 + t]);
        } else {
            int i = id - (49344+73728+18432);
            a.Ar[i] = f2b(a.rw[i]);
        }
    }
    grid.sync();

    // ---------- phase 1: qkv conv1x1 (single-buffer two-stage) ----------
    for (int t = blockIdx.x; t < 768; t += nb){
        ushort* sX = (ushort*)smem;     // 32*264 = 16896 B
        int tile = (t & 7)*96 + (t >> 3);
        int p0 = tile * 32;
        int b0  = p0 / HW;
        int pl0 = p0 % HW;
        int wv = tid >> 6, lane = tid & 63;
        int lm = lane & 15, lk = lane >> 4;
        const ushort* Ap = a.Wqkv + (size_t)(wv*16 + lm)*CC + lk*8;

        // stage T
        for (int i = tid; i < 1024; i += 256){
            int px = i & 31, c8 = i >> 5;
            const float* pt = a.t_feat + ((size_t)(b0*CC + c8*8))*HW + pl0 + px;
            uint u[4];
            #pragma unroll
            for (int j2=0;j2<4;++j2)
                u[j2] = (uint)f2b(pt[(size_t)(2*j2)*HW]) | ((uint)f2b(pt[(size_t)(2*j2+1)*HW])<<16);
            uint4 q4; q4.x=u[0]; q4.y=u[1]; q4.z=u[2]; q4.w=u[3];
            *(uint4*)&sX[(px*33 + c8)*8] = q4;
        }
        __syncthreads();
        // q GEMM
        {
            f32x4 acc[2]; acc[0]=(f32x4){0.f,0.f,0.f,0.f}; acc[1]=(f32x4){0.f,0.f,0.f,0.f};
            #pragma unroll
            for (int k0=0; k0<CC; k0+=32){
                bf16x8 a0 = *(const bf16x8*)(Ap + k0);
                #pragma unroll
                for (int nt=0; nt<2; ++nt){
                    bf16x8 bT = *(const bf16x8*)&sX[((nt*16+lm)*33 + (k0>>3) + lk)*8];
                    acc[nt] = __builtin_amdgcn_mfma_f32_16x16x32_bf16(a0, bT, acc[nt], 0,0,0);
                }
            }
            int ol = wv*16 + lk*4;
            #pragma unroll
            for (int nt=0; nt<2; ++nt){
                int p = p0 + nt*16 + lm;
                uint u0 = (uint)f2b(acc[nt][0]+a.bqkv[ol])   | ((uint)f2b(acc[nt][1]+a.bqkv[ol+1])<<16);
                uint u1 = (uint)f2b(acc[nt][2]+a.bqkv[ol+2]) | ((uint)f2b(acc[nt][3]+a.bqkv[ol+3])<<16);
                *(uint2*)(a.X1 + (size_t)p*128 + ol) = make_uint2(u0, u1);
            }
        }
        __syncthreads();
        // stage S
        for (int i = tid; i < 1024; i += 256){
            int px = i & 31, c8 = i >> 5;
            const float* ps = a.s_feat + ((size_t)(b0*CC + c8*8))*HW + pl0 + px;
            uint u[4];
            #pragma unroll
            for (int j2=0;j2<4;++j2)
                u[j2] = (uint)f2b(ps[(size_t)(2*j2)*HW]) | ((uint)f2b(ps[(size_t)(2*j2+1)*HW])<<16);
            uint4 q4; q4.x=u[0]; q4.y=u[1]; q4.z=u[2]; q4.w=u[3];
            *(uint4*)&sX[(px*33 + c8)*8] = q4;
        }
        __syncthreads();
        // k, v GEMM
        {
            f32x4 ack[2], acv[2];
            ack[0]=(f32x4){0.f,0.f,0.f,0.f}; ack[1]=(f32x4){0.f,0.f,0.f,0.f};
            acv[0]=(f32x4){0.f,0.f,0.f,0.f}; acv[1]=(f32x4){0.f,0.f,0.f,0.f};
            #pragma unroll
            for (int k0=0; k0<CC; k0+=32){
                bf16x8 a1 = *(const bf16x8*)(Ap + 64*CC + k0);
                bf16x8 a2 = *(const bf16x8*)(Ap + 128*CC + k0);
                #pragma unroll
                for (int nt=0; nt<2; ++nt){
                    bf16x8 bS = *(const bf16x8*)&sX[((nt*16+lm)*33 + (k0>>3) + lk)*8];
                    ack[nt] = __builtin_amdgcn_mfma_f32_16x16x32_bf16(a1, bS, ack[nt], 0,0,0);
                    acv[nt] = __builtin_amdgcn_mfma_f32_16x16x32_bf16(a2, bS, acv[nt], 0,0,0);
                }
            }
            int ol = wv*16 + lk*4;
            #pragma unroll
            for (int nt=0; nt<2; ++nt){
                int p = p0 + nt*16 + lm;
                int ob = 64 + ol;
                uint u0 = (uint)f2b(ack[nt][0]+a.bqkv[ob])   | ((uint)f2b(ack[nt][1]+a.bqkv[ob+1])<<16);
                uint u1 = (uint)f2b(ack[nt][2]+a.bqkv[ob+2]) | ((uint)f2b(ack[nt][3]+a.bqkv[ob+3])<<16);
                *(uint2*)(a.X1 + (size_t)p*128 + 64 + ol) = make_uint2(u0, u1);
                #pragma unroll
                for (int j=0;j<4;++j)
                    a.VbT[(size_t)(ol+j)*NPIX + p] = f2b(acv[nt][j] + a.bqkv[128 + ol + j]);
            }
        }
        __syncthreads();
    }
    grid.sync();

    // ---------- phase 2: k_ca (16px tiles, 1536 of them) ----------
    {
        int imw = a.img_w[0];
        float rel = (imw != 640) ? (640.0f/(float)imw) : 1.0f;
        for (int t = blockIdx.x; t < 1536; t += nb){
            float* sS   = (float*)smem;             // 7680 B
            float* sPCf = (float*)(smem + 7680);    // 6400 B
            int r8  = t & 7;
            int kk  = t >> 3;
            int sub = kk % 12;
            int rhi = kk / 12;
            int row = rhi*8 + r8;
            int b   = row >> 6;
            int h   = row & 63;
            int w0  = sub * 16;
            size_t rowbase = (size_t)b*HW + (size_t)h*WW;
            float sf = 0.01f * rel * a.directs[b] * 191.0f;
            int bl = (sf < 0.f) ? (w0 - 64) : w0;
            int wv = tid >> 6, lane = tid & 63;
            int lm = lane & 15, lk = lane >> 4;

            for (int i = tid; i < 400; i += 256)
                *(f32x4*)&sPCf[i*4] = (f32x4){0.f,0.f,0.f,0.f};
            {
                const ushort* Qp = a.X1 + (rowbase + w0 + lm)*128 + lk*8;
                bf16x8 aq0 = *(const bf16x8*)(Qp);
                bf16x8 aq1 = *(const bf16x8*)(Qp + 32);
                for (int xt = wv; xt < 6; xt += 4){
                    int xrow = xt*16 + lm;
                    int gx = bl + xrow;
                    bf16x8 b0 = {0,0,0,0,0,0,0,0}, b1 = {0,0,0,0,0,0,0,0};
                    if (gx >= 0 && gx < WW){
                        const ushort* Kp = a.X1 + (rowbase + gx)*128 + 64 + lk*8;
                        b0 = *(const bf16x8*)(Kp);
                        b1 = *(const bf16x8*)(Kp + 32);
                    }
                    f32x4 acc = {0.f,0.f,0.f,0.f};
                    acc = __builtin_amdgcn_mfma_f32_16x16x32_bf16(aq0, b0, acc, 0,0,0);
                    acc = __builtin_amdgcn_mfma_f32_16x16x32_bf16(aq1, b1, acc, 0,0,0);
                    *(f32x4*)&sS[xrow*STS2 + lk*4] = acc;
                }
            }
            __syncthreads();

            int px  = tid >> 4;
            int l16 = tid & 15;
            int w   = w0 + px;
            size_t n = rowbase + w;
            float wf = (float)w;
            float cost[2]; int xi0[2], xi1[2]; float frk[2];
            #pragma unroll
            for (int t2=0; t2<2; ++t2){
                int d = l16*2 + t2;
                float srcx = fminf(fmaxf(wf + (float)d*sf, 0.f), 191.0f);
                int x0 = (int)floorf(srcx);
                int x1 = min(x0+1, WW-1);
                float fr = srcx - (float)x0;
                int i0 = min(max(x0 - bl, 0), BANDC-1);
                int i1 = min(max(x1 - bl, 0), BANDC-1);
                xi0[t2] = i0; xi1[t2] = i1; frk[t2] = fr;
                float s0 = sS[i0*STS2 + px];
                float s1 = sS[i1*STS2 + px];
                cost[t2] = (s0 + fr*(s1-s0)) * 0.125f;
            }
            *(float2*)(a.C1 + n*DD + l16*2) = make_float2(cost[0], cost[1]);
            float mm = fmaxf(cost[0], cost[1]);
            mm = fmaxf(mm, __shfl_xor(mm, 1));
            mm = fmaxf(mm, __shfl_xor(mm, 2));
            mm = fmaxf(mm, __shfl_xor(mm, 4));
            mm = fmaxf(mm, __shfl_xor(mm, 8));
            float e0 = __expf(cost[0]-mm), e1 = __expf(cost[1]-mm);
            float ss = e0 + e1;
            ss += __shfl_xor(ss, 1);
            ss += __shfl_xor(ss, 2);
            ss += __shfl_xor(ss, 4);
            ss += __shfl_xor(ss, 8);
            float inv = 1.f/ss;
            float p0 = e0*inv, p1 = e1*inv;
            {
                float w1a = p0*frk[0], w0a = p0 - w1a;
                float w1b = p1*frk[1], w0b = p1 - w1b;
                atomicAdd(&sPCf[px*PFS2 + xi0[0]], w0a);
                atomicAdd(&sPCf[px*PFS2 + xi1[0]], w1a);
                atomicAdd(&sPCf[px*PFS2 + xi0[1]], w0b);
                atomicAdd(&sPCf[px*PFS2 + xi1[1]], w1b);
            }
            __syncthreads();

            {
                int mi = wv;
                int c  = mi*16 + lm;
                const ushort* Vp = a.VbT + (size_t)c*NPIX + rowbase + bl;
                f32x4 acc = {0.f,0.f,0.f,0.f};
                #pragma unroll
                for (int kt=0; kt<3; ++kt){
                    int gx = bl + kt*32 + lk*8;
                    bf16x8 av = {0,0,0,0,0,0,0,0};
                    if (gx >= 0 && gx < WW) av = *(const bf16x8*)(Vp + kt*32 + lk*8);
                    f32x4 v0 = *(const f32x4*)&sPCf[lm*PFS2 + kt*32 + lk*8];
                    f32x4 v1 = *(const f32x4*)&sPCf[lm*PFS2 + kt*32 + lk*8 + 4];
                    bf16x8 bbf;
                    #pragma unroll
                    for (int jj=0;jj<4;++jj){
                        bbf[jj]   = (short)f2b(v0[jj]);
                        bbf[jj+4] = (short)f2b(v1[jj]);
                    }
                    acc = __builtin_amdgcn_mfma_f32_16x16x32_bf16(av, bbf, acc, 0,0,0);
                }
                uint u0 = (uint)f2b(acc[0]) | ((uint)f2b(acc[1])<<16);
                uint u1 = (uint)f2b(acc[2]) | ((uint)f2b(acc[3])<<16);
                *(uint2*)(a.Agg + (rowbase + w0 + lm)*64 + wv*16 + lk*4) = make_uint2(u0, u1);
            }
            __syncthreads();
        }
    }
    grid.sync();

    // ---------- phase 3: conv3x3 p1 ----------
    for (int t = blockIdx.x; t < 768; t += nb){
        ushort* sB = (ushort*)smem;   // 26112 B
        int tile = (t & 7)*96 + (t >> 3);
        int n0 = tile * 32;
        int b  = n0 / HW;
        int pl = n0 % HW;
        int h  = pl / WW, w0 = pl % WW;
        int wv = tid >> 6, lane = tid & 63;
        int lm = lane & 15, lk = lane >> 4;

        for (int i = tid; i < 1632; i += 256){
            int dh = i / 544, rem2 = i % 544;
            int c16 = rem2 / 34, x = rem2 % 34;
            int hh = h + dh - 1, wx = w0 + x - 1;
            uint4 val = make_uint4(0,0,0,0);
            if (hh >= 0 && hh < HH && wx >= 0 && wx < WW){
                size_t pix = (size_t)b*HW + (size_t)hh*WW + wx;
                val = (c16 < 8) ? *(const uint4*)(a.X1 + pix*128 + c16*8)
                                : *(const uint4*)(a.Agg + pix*64 + (c16-8)*8);
            }
            *(uint4*)&sB[((dh*16 + c16)*34 + x)*8] = val;
        }
        __syncthreads();

        int mw = wv & 1, nw = wv >> 1;
        const ushort* Ap = a.A1 + (size_t)(mw*32 + lm)*1152 + lk*8;
        f32x4 acc0 = {0.f,0.f,0.f,0.f}, acc1 = {0.f,0.f,0.f,0.f};
        int xb = nw*16 + lm;
        #pragma unroll
        for (int tt=0; tt<9; ++tt){
            int dh = tt/3, dw = tt%3;
            #pragma unroll
            for (int c0=0; c0<128; c0+=32){
                bf16x8 bb = *(const bf16x8*)&sB[((dh*16 + (c0>>3)+lk)*34 + xb + dw)*8];
                bf16x8 a0 = *(const bf16x8*)(Ap + tt*128 + c0);
                bf16x8 a1 = *(const bf16x8*)(Ap + (size_t)16*1152 + tt*128 + c0);
                acc0 = __builtin_amdgcn_mfma_f32_16x16x32_bf16(a0, bb, acc0, 0,0,0);
                acc1 = __builtin_amdgcn_mfma_f32_16x16x32_bf16(a1, bb, acc1, 0,0,0);
            }
        }
        int pg = n0 + nw*16 + lm;
        int o0 = mw*32 + lk*4;
        uint u0 = (uint)f2b(eluf(acc0[0]+a.p1b[o0]))   | ((uint)f2b(eluf(acc0[1]+a.p1b[o0+1]))<<16);
        uint u1 = (uint)f2b(eluf(acc0[2]+a.p1b[o0+2])) | ((uint)f2b(eluf(acc0[3]+a.p1b[o0+3]))<<16);
        *(uint2*)(a.X2 + (size_t)pg*64 + o0) = make_uint2(u0, u1);
        int o1 = o0 + 16;
        uint u2 = (uint)f2b(eluf(acc1[0]+a.p1b[o1]))   | ((uint)f2b(eluf(acc1[1]+a.p1b[o1+1]))<<16);
        uint u3 = (uint)f2b(eluf(acc1[2]+a.p1b[o1+2])) | ((uint)f2b(eluf(acc1[3]+a.p1b[o1+3]))<<16);
        *(uint2*)(a.X2 + (size_t)pg*64 + o1) = make_uint2(u2, u3);
        __syncthreads();
    }
    grid.sync();

    // ---------- phase 4: conv p2 + residual + softmax + final conv1x1 ----------
    for (int t = blockIdx.x; t < 768; t += nb){
        ushort* sT = (ushort*)smem;                    // 16896 B
        float*  sO = (float*)(smem + 16896);           // 4608 B
        ushort* sN = (ushort*)(smem + 16896 + 4608);   // 2560 B
        ushort* sB = sT;
        int tile = (t & 7)*96 + (t >> 3);
        int n0 = tile * 32;
        int b  = n0 / HW;
        int pl = n0 % HW;
        int h  = pl / WW, w0 = pl % WW;
        int wv = tid >> 6, lane = tid & 63;
        int lm = lane & 15, lk = lane >> 4;

        for (int i = tid; i < 816; i += 256){
            int dh = i / 272, rem2 = i % 272;
            int c16 = rem2 / 34, x = rem2 % 34;
            int hh = h + dh - 1, wx = w0 + x - 1;
            uint4 val = make_uint4(0,0,0,0);
            if (hh >= 0 && hh < HH && wx >= 0 && wx < WW)
                val = *(const uint4*)(a.X2 + ((size_t)b*HW + (size_t)hh*WW + wx)*64 + c16*8);
            *(uint4*)&sB[((dh*8 + c16)*34 + x)*8] = val;
        }
        __syncthreads();

        {
            int mw = wv & 1, nw = wv >> 1;
            const ushort* Ap = a.A2 + (size_t)(mw*16 + lm)*576 + lk*8;
            f32x4 acc = {0.f,0.f,0.f,0.f};
            int xb = nw*16 + lm;
            #pragma unroll
            for (int tt=0; tt<9; ++tt){
                int dh = tt/3, dw = tt%3;
                #pragma unroll
                for (int c0=0; c0<64; c0+=32){
                    bf16x8 bb = *(const bf16x8*)&sB[((dh*8 + (c0>>3)+lk)*34 + xb + dw)*8];
                    bf16x8 aw = *(const bf16x8*)(Ap + tt*64 + c0);
                    acc = __builtin_amdgcn_mfma_f32_16x16x32_bf16(aw, bb, acc, 0,0,0);
                }
            }
            int pg = n0 + nw*16 + lm;
            int pll = pg % HW;
            int o = mw*16 + lk*4;
            f32x4 cv = *(const f32x4*)(a.C1 + (size_t)pg*DD + o);
            f32x4 outv;
            #pragma unroll
            for (int j=0;j<4;++j){
                outv[j] = (cv[j] + acc[j] + a.p2b[o+j]) * 0.5f;
                a.cost_out[((size_t)(b*DD + o + j))*HW + pll] = outv[j];
            }
            *(f32x4*)&sO[(nw*16 + lm)*36 + o] = outv;
        }
        __syncthreads();

        {
            int px = tid >> 3;
            int g  = tid & 7;
            f32x4 v = *(const f32x4*)&sO[px*36 + g*4];
            float m = fmaxf(fmaxf(v[0],v[1]), fmaxf(v[2],v[3]));
            m = fmaxf(m, __shfl_xor(m, 1));
            m = fmaxf(m, __shfl_xor(m, 2));
            m = fmaxf(m, __shfl_xor(m, 4));
            float e[4]; float s = 0.f;
            #pragma unroll
            for (int j=0;j<4;++j){ e[j] = __expf(v[j]-m); s += e[j]; }
            s += __shfl_xor(s, 1);
            s += __shfl_xor(s, 2);
            s += __shfl_xor(s, 4);
            float invs = 1.f/s;
            uint u0 = (uint)f2b(e[0]*invs) | ((uint)f2b(e[1]*invs)<<16);
            uint u1 = (uint)f2b(e[2]*invs) | ((uint)f2b(e[3]*invs)<<16);
            *(uint2*)&sN[px*40 + g*4] = make_uint2(u0, u1);
        }
        for (int i = tid; i < 1024; i += 256){
            int px = i & 31, c8 = i >> 5;
            const float* pt = a.t_feat + ((size_t)(b*CC + c8*8))*HW + pl + px;
            uint u[4];
            #pragma unroll
            for (int j2=0;j2<4;++j2)
                u[j2] = (uint)f2b(pt[(size_t)(2*j2)*HW]) | ((uint)f2b(pt[(size_t)(2*j2+1)*HW])<<16);
            uint4 q4; q4.x=u[0]; q4.y=u[1]; q4.z=u[2]; q4.w=u[3];
            *(uint4*)&sT[(px*33 + c8)*8] = q4;
        }
        __syncthreads();

        {
            f32x4 acc[4][2];
            #pragma unroll
            for (int mi=0;mi<4;++mi){ acc[mi][0]=(f32x4){0.f,0.f,0.f,0.f}; acc[mi][1]=(f32x4){0.f,0.f,0.f,0.f}; }
            const ushort* Ap = a.Ar + (size_t)(wv*64 + lm)*288 + lk*8;
            #pragma unroll
            for (int k0=0; k0<288; k0+=32){
                bf16x8 aw[4];
                #pragma unroll
                for (int mi=0;mi<4;++mi) aw[mi] = *(const bf16x8*)(Ap + (size_t)mi*16*288 + k0);
                #pragma unroll
                for (int nt=0; nt<2; ++nt){
                    int prow = nt*16 + lm;
                    bf16x8 bb = (k0 < 256) ? *(const bf16x8*)&sT[(prow*33 + (k0>>3) + lk)*8]
                                           : *(const bf16x8*)&sN[(prow*5 + lk)*8];
                    #pragma unroll
                    for (int mi=0;mi<4;++mi)
                        acc[mi][nt] = __builtin_amdgcn_mfma_f32_16x16x32_bf16(aw[mi], bb, acc[mi][nt], 0,0,0);
                }
            }
            #pragma unroll
            for (int mi=0;mi<4;++mi){
                int o = wv*64 + mi*16 + lk*4;
                #pragma unroll
                for (int nt=0; nt<2; ++nt){
                    int p = n0 + nt*16 + lm;
                    int bb2 = p / HW, pl2 = p % HW;
                    #pragma unroll
                    for (int j=0;j<4;++j)
                        a.xout[((size_t)(bb2*CC + o + j))*HW + pl2] = eluf(acc[mi][nt][j] + a.rb[o+j]);
                }
            }
        }
        __syncthreads();
    }
}

// ==================== FALLBACK: proven 5-kernel path ====================
__global__ __launch_bounds__(256) void k_prep_w(
    const float* __restrict__ qw, const float* __restrict__ qb,
    const float* __restrict__ kw, const float* __restrict__ kb,
    const float* __restrict__ vw, const float* __restrict__ vb,
    const float* __restrict__ p1w, const float* __restrict__ p2w,
    const float* __restrict__ rw,
    ushort* __restrict__ Wqkv, float* __restrict__ bqkv,
    ushort* __restrict__ A1, ushort* __restrict__ A2, ushort* __restrict__ Ar)
{
    int id = blockIdx.x*256 + threadIdx.x;
    if (id < 49152) {
        int o = id / 256, c = id % 256;
        float v = (o<64)? qw[o*256+c] : (o<128)? kw[(o-64)*256+c] : vw[(o-128)*256+c];
        Wqkv[id] = f2b(v);
    } else if (id < 49344) {
        int o = id - 49152;
        bqkv[o] = (o<64)? qb[o] : (o<128)? kb[o-64] : vb[o-128];
    } else if (id < 49344+73728) {
        int i = id - 49344;
        int o = i/1152, r = i%1152, t = r/128, ci = r%128;
        A1[i] = f2b(p1w[(size_t)(o*128+ci)*9 + t]);
    } else if (id < 49344+73728+18432) {
        int i = id - (49344+73728);
        int o = i/576, r = i%576, t = r/64, ci = r%64;
        A2[i] = f2b(p2w[(size_t)(o*64+ci)*9 + t]);
    } else if (id < 49344+73728+18432+73728) {
        int i = id - (49344+73728+18432);
        Ar[i] = f2b(rw[i]);
    }
}

__global__ __launch_bounds__(256) void g_qkv(
    const float* __restrict__ t_feat, const float* __restrict__ s_feat,
    const ushort* __restrict__ Wqkv, const float* __restrict__ bqkv,
    ushort* __restrict__ X1, ushort* __restrict__ VbT)
{
    __shared__ ushort sT[32*264];
    __shared__ ushort sS[32*264];
    int tid = threadIdx.x;
    int bid = blockIdx.x;
    int tile = (bid & 7)*96 + (bid >> 3);
    int p0 = tile * 32;
    int b0  = p0 / HW;
    int pl0 = p0 % HW;

    for (int i = tid; i < 1024; i += 256){
        int px = i & 31, c8 = i >> 5;
        const float* pt = t_feat + ((size_t)(b0*CC + c8*8))*HW + pl0 + px;
        const float* ps = s_feat + ((size_t)(b0*CC + c8*8))*HW + pl0 + px;
        uint ut[4], us[4];
        #pragma unroll
        for (int j2=0;j2<4;++j2){
            ut[j2] = (uint)f2b(pt[(size_t)(2*j2)*HW]) | ((uint)f2b(pt[(size_t)(2*j2+1)*HW])<<16);
            us[j2] = (uint)f2b(ps[(size_t)(2*j2)*HW]) | ((uint)f2b(ps[(size_t)(2*j2+1)*HW])<<16);
        }
        uint4 qt; qt.x=ut[0]; qt.y=ut[1]; qt.z=ut[2]; qt.w=ut[3];
        uint4 qs; qs.x=us[0]; qs.y=us[1]; qs.z=us[2]; qs.w=us[3];
        *(uint4*)&sT[(px*33 + c8)*8] = qt;
        *(uint4*)&sS[(px*33 + c8)*8] = qs;
    }
    __syncthreads();

    int wv = tid >> 6, lane = tid & 63;
    int lm = lane & 15, lk = lane >> 4;
    f32x4 acc[3][2];
    #pragma unroll
    for (int g=0;g<3;++g){ acc[g][0]=(f32x4){0.f,0.f,0.f,0.f}; acc[g][1]=(f32x4){0.f,0.f,0.f,0.f}; }
    const ushort* Ap = Wqkv + (size_t)(wv*16 + lm)*CC + lk*8;

    #pragma unroll
    for (int k0=0; k0<CC; k0+=32){
        bf16x8 a0 = *(const bf16x8*)(Ap + k0);
        bf16x8 a1 = *(const bf16x8*)(Ap + 64*CC + k0);
        bf16x8 a2 = *(const bf16x8*)(Ap + 128*CC + k0);
        #pragma unroll
        for (int nt=0; nt<2; ++nt){
            int ch = (nt*16+lm)*33 + (k0>>3) + lk;
            bf16x8 bT = *(const bf16x8*)&sT[ch*8];
            bf16x8 bS = *(const bf16x8*)&sS[ch*8];
            acc[0][nt] = __builtin_amdgcn_mfma_f32_16x16x32_bf16(a0, bT, acc[0][nt], 0,0,0);
            acc[1][nt] = __builtin_amdgcn_mfma_f32_16x16x32_bf16(a1, bS, acc[1][nt], 0,0,0);
            acc[2][nt] = __builtin_amdgcn_mfma_f32_16x16x32_bf16(a2, bS, acc[2][nt], 0,0,0);
        }
    }
    int ol = wv*16 + lk*4;
    #pragma unroll
    for (int nt=0; nt<2; ++nt){
        int p = p0 + nt*16 + lm;
        {
            uint u0 = (uint)f2b(acc[0][nt][0]+bqkv[ol])   | ((uint)f2b(acc[0][nt][1]+bqkv[ol+1])<<16);
            uint u1 = (uint)f2b(acc[0][nt][2]+bqkv[ol+2]) | ((uint)f2b(acc[0][nt][3]+bqkv[ol+3])<<16);
            *(uint2*)(X1 + (size_t)p*128 + ol) = make_uint2(u0, u1);
        }
        {
            int ob = 64 + ol;
            uint u0 = (uint)f2b(acc[1][nt][0]+bqkv[ob])   | ((uint)f2b(acc[1][nt][1]+bqkv[ob+1])<<16);
            uint u1 = (uint)f2b(acc[1][nt][2]+bqkv[ob+2]) | ((uint)f2b(acc[1][nt][3]+bqkv[ob+3])<<16);
            *(uint2*)(X1 + (size_t)p*128 + 64 + ol) = make_uint2(u0, u1);
        }
        #pragma unroll
        for (int j=0;j<4;++j)
            VbT[(size_t)(ol+j)*NPIX + p] = f2b(acc[2][nt][j] + bqkv[128 + ol + j]);
    }
}

__global__ __launch_bounds__(256) void k_ca(
    const ushort* __restrict__ X1, const ushort* __restrict__ VbT,
    const float* __restrict__ directs, const int* __restrict__ img_w_p,
    float* __restrict__ C1, ushort* __restrict__ Agg)
{
    __shared__ float sS[BANDC*STS2];
    __shared__ float sPCf[16*PFS2];
    int tid = threadIdx.x;
    int j   = blockIdx.x;
    int r8  = j & 7;
    int kk  = j >> 3;
    int sub = kk % 12;
    int rhi = kk / 12;
    int row = rhi*8 + r8;
    int b   = row >> 6;
    int h   = row & 63;
    int w0  = sub * 16;
    size_t rowbase = (size_t)b*HW + (size_t)h*WW;

    int imw = img_w_p[0];
    float rel = (imw != 640) ? (640.0f/(float)imw) : 1.0f;
    float sf = 0.01f * rel * directs[b] * 191.0f;
    int bl = (sf < 0.f) ? (w0 - 64) : w0;

    int wv = tid >> 6, lane = tid & 63;
    int lm = lane & 15, lk = lane >> 4;

    for (int i = tid; i < 400; i += 256)
        *(f32x4*)&sPCf[i*4] = (f32x4){0.f,0.f,0.f,0.f};
    {
        const ushort* Qp = X1 + (rowbase + w0 + lm)*128 + lk*8;
        bf16x8 aq0 = *(const bf16x8*)(Qp);
        bf16x8 aq1 = *(const bf16x8*)(Qp + 32);
        for (int xt = wv; xt < 6; xt += 4){
            int xrow = xt*16 + lm;
            int gx = bl + xrow;
            bf16x8 b0 = {0,0,0,0,0,0,0,0}, b1 = {0,0,0,0,0,0,0,0};
            if (gx >= 0 && gx < WW){
                const ushort* Kp = X1 + (rowbase + gx)*128 + 64 + lk*8;
                b0 = *(const bf16x8*)(Kp);
                b1 = *(const bf16x8*)(Kp + 32);
            }
            f32x4 acc = {0.f,0.f,0.f,0.f};
            acc = __builtin_amdgcn_mfma_f32_16x16x32_bf16(aq0, b0, acc, 0,0,0);
            acc = __builtin_amdgcn_mfma_f32_16x16x32_bf16(aq1, b1, acc, 0,0,0);
            *(f32x4*)&sS[xrow*STS2 + lk*4] = acc;
        }
    }
    __syncthreads();

    int px  = tid >> 4;
    int l16 = tid & 15;
    int w   = w0 + px;
    size_t n = rowbase + w;
    float wf = (float)w;

    float cost[2]; int xi0[2], xi1[2]; float frk[2];
    #pragma unroll
    for (int t=0; t<2; ++t){
        int d = l16*2 + t;
        float srcx = fminf(fmaxf(wf + (float)d*sf, 0.f), 191.0f);
        int x0 = (int)floorf(srcx);
        int x1 = min(x0+1, WW-1);
        float fr = srcx - (float)x0;
        int i0 = min(max(x0 - bl, 0), BANDC-1);
        int i1 = min(max(x1 - bl, 0), BANDC-1);
        xi0[t] = i0; xi1[t] = i1; frk[t] = fr;
        float s0 = sS[i0*STS2 + px];
        float s1 = sS[i1*STS2 + px];
        cost[t] = (s0 + fr*(s1-s0)) * 0.125f;
    }
    *(float2*)(C1 + n*DD + l16*2) = make_float2(cost[0], cost[1]);
    float mm = fmaxf(cost[0], cost[1]);
    mm = fmaxf(mm, __shfl_xor(mm, 1));
    mm = fmaxf(mm, __shfl_xor(mm, 2));
    mm = fmaxf(mm, __shfl_xor(mm, 4));
    mm = fmaxf(mm, __shfl_xor(mm, 8));
    float e0 = __expf(cost[0]-mm), e1 = __expf(cost[1]-mm);
    float ss = e0 + e1;
    ss += __shfl_xor(ss, 1);
    ss += __shfl_xor(ss, 2);
    ss += __shfl_xor(ss, 4);
    ss += __shfl_xor(ss, 8);
    float inv = 1.f/ss;
    float p0 = e0*inv, p1 = e1*inv;
    {
        float w1a = p0*frk[0], w0a = p0 - w1a;
        float w1b = p1*frk[1], w0b = p1 - w1b;
        atomicAdd(&sPCf[px*PFS2 + xi0[0]], w0a);
        atomicAdd(&sPCf[px*PFS2 + xi1[0]], w1a);
        atomicAdd(&sPCf[px*PFS2 + xi0[1]], w0b);
        atomicAdd(&sPCf[px*PFS2 + xi1[1]], w1b);
    }
    __syncthreads();

    {
        int mi = wv;
        int c  = mi*16 + lm;
        const ushort* Vp = VbT + (size_t)c*NPIX + rowbase + bl;
        f32x4 acc = {0.f,0.f,0.f,0.f};
        #pragma unroll
        for (int kt=0; kt<3; ++kt){
            int gx = bl + kt*32 + lk*8;
            bf16x8 av = {0,0,0,0,0,0,0,0};
            if (gx >= 0 && gx < WW) av = *(const bf16x8*)(Vp + kt*32 + lk*8);
            f32x4 v0 = *(const f32x4*)&sPCf[lm*PFS2 + kt*32 + lk*8];
            f32x4 v1 = *(const f32x4*)&sPCf[lm*PFS2 + kt*32 + lk*8 + 4];
            bf16x8 bbf;
            #pragma unroll
            for (int jj=0;jj<4;++jj){
                bbf[jj]   = (short)f2b(v0[jj]);
                bbf[jj+4] = (short)f2b(v1[jj]);
            }
            acc = __builtin_amdgcn_mfma_f32_16x16x32_bf16(av, bbf, acc, 0,0,0);
        }
        uint u0 = (uint)f2b(acc[0]) | ((uint)f2b(acc[1])<<16);
        uint u1 = (uint)f2b(acc[2]) | ((uint)f2b(acc[3])<<16);
        *(uint2*)(Agg + (rowbase + w0 + lm)*64 + mi*16 + lk*4) = make_uint2(u0, u1);
    }
}

__global__ __launch_bounds__(256) void g_conv1(
    const ushort* __restrict__ X1, const ushort* __restrict__ Agg,
    const ushort* __restrict__ A1, const float* __restrict__ p1b,
    ushort* __restrict__ X2)
{
    __shared__ ushort sB[3*16*34*8];
    int tid = threadIdx.x;
    int wv = tid >> 6, lane = tid & 63;
    int lm = lane & 15, lk = lane >> 4;
    int bid = blockIdx.x;
    int tile = (bid & 7)*96 + (bid >> 3);
    int n0 = tile * 32;
    int b  = n0 / HW;
    int pl = n0 % HW;
    int h  = pl / WW, w0 = pl % WW;

    for (int i = tid; i < 1632; i += 256){
        int dh = i / 544, rem2 = i % 544;
        int c16 = rem2 / 34, x = rem2 % 34;
        int hh = h + dh - 1, wx = w0 + x - 1;
        uint4 val = make_uint4(0,0,0,0);
        if (hh >= 0 && hh < HH && wx >= 0 && wx < WW){
            size_t pix = (size_t)b*HW + (size_t)hh*WW + wx;
            val = (c16 < 8) ? *(const uint4*)(X1 + pix*128 + c16*8)
                            : *(const uint4*)(Agg + pix*64 + (c16-8)*8);
        }
        *(uint4*)&sB[((dh*16 + c16)*34 + x)*8] = val;
    }
    __syncthreads();

    int mw = wv & 1, nw = wv >> 1;
    const ushort* Ap = A1 + (size_t)(mw*32 + lm)*1152 + lk*8;
    f32x4 acc0 = {0.f,0.f,0.f,0.f}, acc1 = {0.f,0.f,0.f,0.f};
    int xb = nw*16 + lm;
    #pragma unroll
    for (int t=0; t<9; ++t){
        int dh = t/3, dw = t%3;
        #pragma unroll
        for (int c0=0; c0<128; c0+=32){
            bf16x8 bb = *(const bf16x8*)&sB[((dh*16 + (c0>>3)+lk)*34 + xb + dw)*8];
            bf16x8 a0 = *(const bf16x8*)(Ap + t*128 + c0);
            bf16x8 a1 = *(const bf16x8*)(Ap + (size_t)16*1152 + t*128 + c0);
            acc0 = __builtin_amdgcn_mfma_f32_16x16x32_bf16(a0, bb, acc0, 0,0,0);
            acc1 = __builtin_amdgcn_mfma_f32_16x16x32_bf16(a1, bb, acc1, 0,0,0);
        }
    }
    int pg = n0 + nw*16 + lm;
    int o0 = mw*32 + lk*4;
    {
        uint u0 = (uint)f2b(eluf(acc0[0]+p1b[o0]))   | ((uint)f2b(eluf(acc0[1]+p1b[o0+1]))<<16);
        uint u1 = (uint)f2b(eluf(acc0[2]+p1b[o0+2])) | ((uint)f2b(eluf(acc0[3]+p1b[o0+3]))<<16);
        *(uint2*)(X2 + (size_t)pg*64 + o0) = make_uint2(u0, u1);
        int o1 = o0 + 16;
        uint u2 = (uint)f2b(eluf(acc1[0]+p1b[o1]))   | ((uint)f2b(eluf(acc1[1]+p1b[o1+1]))<<16);
        uint u3 = (uint)f2b(eluf(acc1[2]+p1b[o1+2])) | ((uint)f2b(eluf(acc1[3]+p1b[o1+3]))<<16);
        *(uint2*)(X2 + (size_t)pg*64 + o1) = make_uint2(u2, u3);
    }
}

__global__ __launch_bounds__(256) void g_conv2final(
    const ushort* __restrict__ X2, const ushort* __restrict__ A2,
    const float* __restrict__ p2b, const float* __restrict__ C1,
    const float* __restrict__ t_feat, const ushort* __restrict__ Ar,
    const float* __restrict__ rb,
    float* __restrict__ cost_out, float* __restrict__ xout)
{
    __shared__ ushort sT[32*264];
    __shared__ float  sO[32*36];
    __shared__ ushort sN[32*40];
    ushort* sB = sT;
    int tid = threadIdx.x;
    int wv = tid >> 6, lane = tid & 63;
    int lm = lane & 15, lk = lane >> 4;
    int bid = blockIdx.x;
    int tile = (bid & 7)*96 + (bid >> 3);
    int n0 = tile * 32;
    int b  = n0 / HW;
    int pl = n0 % HW;
    int h  = pl / WW, w0 = pl % WW;

    for (int i = tid; i < 816; i += 256){
        int dh = i / 272, rem2 = i % 272;
        int c16 = rem2 / 34, x = rem2 % 34;
        int hh = h + dh - 1, wx = w0 + x - 1;
        uint4 val = make_uint4(0,0,0,0);
        if (hh >= 0 && hh < HH && wx >= 0 && wx < WW)
            val = *(const uint4*)(X2 + ((size_t)b*HW + (size_t)hh*WW + wx)*64 + c16*8);
        *(uint4*)&sB[((dh*8 + c16)*34 + x)*8] = val;
    }
    __syncthreads();

    {
        int mw = wv & 1, nw = wv >> 1;
        const ushort* Ap = A2 + (size_t)(mw*16 + lm)*576 + lk*8;
        f32x4 acc = {0.f,0.f,0.f,0.f};
        int xb = nw*16 + lm;
        #pragma unroll
        for (int t=0; t<9; ++t){
            int dh = t/3, dw = t%3;
            #pragma unroll
            for (int c0=0; c0<64; c0+=32){
                bf16x8 bb = *(const bf16x8*)&sB[((dh*8 + (c0>>3)+lk)*34 + xb + dw)*8];
                bf16x8 aw = *(const bf16x8*)(Ap + t*64 + c0);
                acc = __builtin_amdgcn_mfma_f32_16x16x32_bf16(aw, bb, acc, 0,0,0);
            }
        }
        int pg = n0 + nw*16 + lm;
        int pll = pg % HW;
        int o = mw*16 + lk*4;
        f32x4 cv = *(const f32x4*)(C1 + (size_t)pg*DD + o);
        f32x4 outv;
        #pragma unroll
        for (int j=0;j<4;++j){
            outv[j] = (cv[j] + acc[j] + p2b[o+j]) * 0.5f;
            cost_out[((size_t)(b*DD + o + j))*HW + pll] = outv[j];
        }
        *(f32x4*)&sO[(nw*16 + lm)*36 + o] = outv;
    }
    __syncthreads();

    {
        int px = tid >> 3;
        int g  = tid & 7;
        f32x4 v = *(const f32x4*)&sO[px*36 + g*4];
        float m = fmaxf(fmaxf(v[0],v[1]), fmaxf(v[2],v[3]));
        m = fmaxf(m, __shfl_xor(m, 1));
        m = fmaxf(m, __shfl_xor(m, 2));
        m = fmaxf(m, __shfl_xor(m, 4));
        float e[4]; float s = 0.f;
        #pragma unroll
        for (int j=0;j<4;++j){ e[j] = __expf(v[j]-m); s += e[j]; }
        s += __shfl_xor(s, 1);
        s += __shfl_xor(s, 2);
        s += __shfl_xor(s, 4);
        float invs = 1.f/s;
        uint u0 = (uint)f2b(e[0]*invs) | ((uint)f2b(e[1]*invs)<<16);
        uint u1 = (uint)f2b(e[2]*invs) | ((uint)f2b(e[3]*invs)<<16);
        *(uint2*)&sN[px*40 + g*4] = make_uint2(u0, u1);
    }
    for (int i = tid; i < 1024; i += 256){
        int px = i & 31, c8 = i >> 5;
        const float* pt = t_feat + ((size_t)(b*CC + c8*8))*HW + pl + px;
        uint u[4];
        #pragma unroll
        for (int j2=0;j2<4;++j2)
            u[j2] = (uint)f2b(pt[(size_t)(2*j2)*HW]) | ((uint)f2b(pt[(size_t)(2*j2+1)*HW])<<16);
        uint4 q4; q4.x=u[0]; q4.y=u[1]; q4.z=u[2]; q4.w=u[3];
        *(uint4*)&sT[(px*33 + c8)*8] = q4;
    }
    __syncthreads();

    {
        f32x4 acc[4][2];
        #pragma unroll
        for (int mi=0;mi<4;++mi){ acc[mi][0]=(f32x4){0.f,0.f,0.f,0.f}; acc[mi][1]=(f32x4){0.f,0.f,0.f,0.f}; }
        const ushort* Ap = Ar + (size_t)(wv*64 + lm)*288 + lk*8;

        #pragma unroll
        for (int k0=0; k0<288; k0+=32){
            bf16x8 aw[4];
            #pragma unroll
            for (int mi=0;mi<4;++mi) aw[mi] = *(const bf16x8*)(Ap + (size_t)mi*16*288 + k0);
            #pragma unroll
            for (int nt=0; nt<2; ++nt){
                int prow = nt*16 + lm;
                bf16x8 bb = (k0 < 256) ? *(const bf16x8*)&sT[(prow*33 + (k0>>3) + lk)*8]
                                       : *(const bf16x8*)&sN[(prow*5 + lk)*8];
                #pragma unroll
                for (int mi=0;mi<4;++mi)
                    acc[mi][nt] = __builtin_amdgcn_mfma_f32_16x16x32_bf16(aw[mi], bb, acc[mi][nt], 0,0,0);
            }
        }
        #pragma unroll
        for (int mi=0;mi<4;++mi){
            int o = wv*64 + mi*16 + lk*4;
            #pragma unroll
            for (int nt=0; nt<2; ++nt){
                int p = n0 + nt*16 + lm;
                int bb2 = p / HW, pl2 = p % HW;
                #pragma unroll
                for (int j=0;j<4;++j)
                    xout[((size_t)(bb2*CC + o + j))*HW + pl2] = eluf(acc[mi][nt][j] + rb[o+j]);
            }
        }
    }
}

extern "C" void kernel_launch(void* const* d_in, const int* in_sizes, int n_in,
                              void* d_out, int out_size, void* d_ws, size_t ws_size,
                              hipStream_t stream)
{
    const float* t_feat = (const float*)d_in[0];
    const float* s_feat = (const float*)d_in[1];
    const float* directs= (const float*)d_in[2];
    const float* qw = (const float*)d_in[3];
    const float* qb = (const float*)d_in[4];
    const float* kw = (const float*)d_in[5];
    const float* kb = (const float*)d_in[6];
    const float* vw = (const float*)d_in[7];
    const float* vb = (const float*)d_in[8];
    const float* p1w= (const float*)d_in[9];
    const float* p1b= (const float*)d_in[10];
    const float* p2w= (const float*)d_in[11];
    const float* p2b= (const float*)d_in[12];
    const float* rw = (const float*)d_in[13];
    const float* rb = (const float*)d_in[14];
    const int* img_w= (const int*)d_in[15];

    char* wsb = (char*)d_ws;
    char*  tsreg = wsb + 12582912;
    ushort* X2   = (ushort*)tsreg;
    float*  C1   = (float*)(tsreg + 3145728);
    ushort* Agg  = (ushort*)(tsreg + 6291456);
    ushort* X1   = (ushort*)(wsb + 25165824);
    ushort* VbT  = (ushort*)(wsb + 31457280);
    ushort* Wqkv = (ushort*)(wsb + 34603008);
    float*  bqkv = (float*) (wsb + 34701312);
    ushort* A1   = (ushort*)(wsb + 34702336);
    ushort* A2   = (ushort*)(wsb + 34849792);
    ushort* Ar   = (ushort*)(wsb + 34886656);
    if (ws_size < 35034112) return;

    float* xout     = (float*)d_out;
    float* cost_out = xout + (size_t)BB*CC*HW;

    MArgs ma;
    ma.t_feat=t_feat; ma.s_feat=s_feat; ma.directs=directs; ma.img_w=img_w;
    ma.qw=qw; ma.qb=qb; ma.kw=kw; ma.kb=kb; ma.vw=vw; ma.vb=vb;
    ma.p1w=p1w; ma.p1b=p1b; ma.p2w=p2w; ma.p2b=p2b; ma.rw=rw; ma.rb=rb;
    ma.Wqkv=Wqkv; ma.bqkv=bqkv; ma.A1=A1; ma.A2=A2; ma.Ar=Ar;
    ma.X1=X1; ma.VbT=VbT; ma.X2=X2; ma.C1=C1; ma.Agg=Agg;
    ma.cost_out=cost_out; ma.xout=xout;

    int nbpc = 0;
    hipError_t qe = hipOccupancyMaxActiveBlocksPerMultiprocessor(&nbpc, mega, 256, 0);
    int grid = (qe == hipSuccess && nbpc > 0) ? nbpc * 256 : 1024;
    if (grid > 1536) grid = 1536;

    void* args[] = { &ma };
    hipError_t le = hipLaunchCooperativeKernel((const void*)mega, dim3(grid), dim3(256),
                                               args, 0, stream);
    if (le != hipSuccess) {
        (void)hipGetLastError();   // clear error state
        k_prep_w    <<<841,  256, 0, stream>>>(qw,qb,kw,kb,vw,vb,p1w,p2w,rw,
                                               Wqkv,bqkv,A1,A2,Ar);
        g_qkv       <<<768,  256, 0, stream>>>(t_feat, s_feat, Wqkv, bqkv, X1, VbT);
        k_ca        <<<1536, 256, 0, stream>>>(X1, VbT, directs, img_w, C1, Agg);
        g_conv1     <<<768,  256, 0, stream>>>(X1, Agg, A1, p1b, X2);
        g_conv2final<<<768,  256, 0, stream>>>(X2, A2, p2b, C1, t_feat, Ar, rb,
                                               cost_out, xout);
    }
}

// Round 16
// 114.672 us; speedup vs baseline: 3.4911x; 3.4911x over previous
//
#include <hip/hip_runtime.h>

#define BB 2
#define CC 256
#define CQ 64
#define DD 32
#define HH 64
#define WW 192
#define HW (HH*WW)     // 12288
#define NPIX (BB*HW)   // 24576

typedef __attribute__((ext_vector_type(8))) short bf16x8;
typedef __attribute__((ext_vector_type(4))) float f32x4;

__device__ __forceinline__ float b2f(ushort s){ return __uint_as_float(((uint)s)<<16); }
__device__ __forceinline__ ushort f2b(float f){
    uint u = __float_as_uint(f);
    return (ushort)((u + 0x7fffu + ((u>>16)&1u)) >> 16);
}
__device__ __forceinline__ float eluf(float v){ return v > 0.f ? v : (__expf(v)-1.f); }

// load 8 consecutive f32 and round to bf16 fragment (identical bits to prepped path)
__device__ __forceinline__ bf16x8 ldw8(const float* __restrict__ p){
    float4 f0 = *(const float4*)(p);
    float4 f1 = *(const float4*)(p + 4);
    bf16x8 r;
    r[0]=(short)f2b(f0.x); r[1]=(short)f2b(f0.y); r[2]=(short)f2b(f0.z); r[3]=(short)f2b(f0.w);
    r[4]=(short)f2b(f1.x); r[5]=(short)f2b(f1.y); r[6]=(short)f2b(f1.z); r[7]=(short)f2b(f1.w);
    return r;
}

// ---------- G1: qkv conv1x1; A1/A2 weight-prep preamble (syncless);
//             qkv weights converted on-the-fly from f32 ----------
__global__ __launch_bounds__(256) void g_qkv(
    const float* __restrict__ t_feat, const float* __restrict__ s_feat,
    const float* __restrict__ qw, const float* __restrict__ qb,
    const float* __restrict__ kw, const float* __restrict__ kb,
    const float* __restrict__ vw, const float* __restrict__ vb,
    const float* __restrict__ p1w, const float* __restrict__ p2w,
    ushort* __restrict__ A1, ushort* __restrict__ A2,
    ushort* __restrict__ X1, ushort* __restrict__ VbT)
{
    __shared__ ushort sT[32*264];
    __shared__ ushort sS[32*264];
    int tid = threadIdx.x;
    int bid = blockIdx.x;

    // preamble: prep A1/A2 (consumed by LATER kernels; no ordering needed here)
    {
        int id = bid*256 + tid;
        if (id < 73728){
            int o = id/1152, r = id%1152, t = r/128, ci = r%128;
            A1[id] = f2b(p1w[(size_t)(o*128+ci)*9 + t]);
        } else if (id < 73728+18432){
            int i = id - 73728;
            int o = i/576, r = i%576, t = r/64, ci = r%64;
            A2[i] = f2b(p2w[(size_t)(o*64+ci)*9 + t]);
        }
    }

    int tile = (bid & 7)*96 + (bid >> 3);
    int p0 = tile * 32;
    int b0  = p0 / HW;
    int pl0 = p0 % HW;

    for (int i = tid; i < 1024; i += 256){
        int px = i & 31, c8 = i >> 5;
        const float* pt = t_feat + ((size_t)(b0*CC + c8*8))*HW + pl0 + px;
        const float* ps = s_feat + ((size_t)(b0*CC + c8*8))*HW + pl0 + px;
        uint ut[4], us[4];
        #pragma unroll
        for (int j2=0;j2<4;++j2){
            ut[j2] = (uint)f2b(pt[(size_t)(2*j2)*HW]) | ((uint)f2b(pt[(size_t)(2*j2+1)*HW])<<16);
            us[j2] = (uint)f2b(ps[(size_t)(2*j2)*HW]) | ((uint)f2b(ps[(size_t)(2*j2+1)*HW])<<16);
        }
        uint4 qt; qt.x=ut[0]; qt.y=ut[1]; qt.z=ut[2]; qt.w=ut[3];
        uint4 qs; qs.x=us[0]; qs.y=us[1]; qs.z=us[2]; qs.w=us[3];
        *(uint4*)&sT[(px*33 + c8)*8] = qt;
        *(uint4*)&sS[(px*33 + c8)*8] = qs;
    }
    __syncthreads();

    int wv = tid >> 6, lane = tid & 63;
    int lm = lane & 15, lk = lane >> 4;
    f32x4 acc[3][2];
    #pragma unroll
    for (int g=0;g<3;++g){ acc[g][0]=(f32x4){0.f,0.f,0.f,0.f}; acc[g][1]=(f32x4){0.f,0.f,0.f,0.f}; }
    size_t wofs = (size_t)(wv*16 + lm)*CC + lk*8;
    const float* qp = qw + wofs;
    const float* kp = kw + wofs;
    const float* vp = vw + wofs;

    #pragma unroll
    for (int k0=0; k0<CC; k0+=32){
        bf16x8 a0 = ldw8(qp + k0);
        bf16x8 a1 = ldw8(kp + k0);
        bf16x8 a2 = ldw8(vp + k0);
        #pragma unroll
        for (int nt=0; nt<2; ++nt){
            int ch = (nt*16+lm)*33 + (k0>>3) + lk;
            bf16x8 bT = *(const bf16x8*)&sT[ch*8];
            bf16x8 bS = *(const bf16x8*)&sS[ch*8];
            acc[0][nt] = __builtin_amdgcn_mfma_f32_16x16x32_bf16(a0, bT, acc[0][nt], 0,0,0);
            acc[1][nt] = __builtin_amdgcn_mfma_f32_16x16x32_bf16(a1, bS, acc[1][nt], 0,0,0);
            acc[2][nt] = __builtin_amdgcn_mfma_f32_16x16x32_bf16(a2, bS, acc[2][nt], 0,0,0);
        }
    }
    int ol = wv*16 + lk*4;
    #pragma unroll
    for (int nt=0; nt<2; ++nt){
        int p = p0 + nt*16 + lm;
        {
            uint u0 = (uint)f2b(acc[0][nt][0]+qb[ol])   | ((uint)f2b(acc[0][nt][1]+qb[ol+1])<<16);
            uint u1 = (uint)f2b(acc[0][nt][2]+qb[ol+2]) | ((uint)f2b(acc[0][nt][3]+qb[ol+3])<<16);
            *(uint2*)(X1 + (size_t)p*128 + ol) = make_uint2(u0, u1);
        }
        {
            uint u0 = (uint)f2b(acc[1][nt][0]+kb[ol])   | ((uint)f2b(acc[1][nt][1]+kb[ol+1])<<16);
            uint u1 = (uint)f2b(acc[1][nt][2]+kb[ol+2]) | ((uint)f2b(acc[1][nt][3]+kb[ol+3])<<16);
            *(uint2*)(X1 + (size_t)p*128 + 64 + ol) = make_uint2(u0, u1);
        }
        #pragma unroll
        for (int j=0;j<4;++j)
            VbT[(size_t)(ol+j)*NPIX + p] = f2b(acc[2][nt][j] + vb[ol + j]);
    }
}

// ---------- k_ca: MFMA-banded, 2-barrier, 16px/block, 256 thr (R14-proven) ----------
#define BANDC 96
#define STS2 20
#define PFS2 100
__global__ __launch_bounds__(256) void k_ca(
    const ushort* __restrict__ X1, const ushort* __restrict__ VbT,
    const float* __restrict__ directs, const int* __restrict__ img_w_p,
    float* __restrict__ C1, ushort* __restrict__ Agg)
{
    __shared__ float sS[BANDC*STS2];
    __shared__ float sPCf[16*PFS2];
    int tid = threadIdx.x;
    int j   = blockIdx.x;
    int r8  = j & 7;
    int kk  = j >> 3;
    int sub = kk % 12;
    int rhi = kk / 12;
    int row = rhi*8 + r8;
    int b   = row >> 6;
    int h   = row & 63;
    int w0  = sub * 16;
    size_t rowbase = (size_t)b*HW + (size_t)h*WW;

    int imw = img_w_p[0];
    float rel = (imw != 640) ? (640.0f/(float)imw) : 1.0f;
    float sf = 0.01f * rel * directs[b] * 191.0f;
    int bl = (sf < 0.f) ? (w0 - 64) : w0;

    int wv = tid >> 6, lane = tid & 63;
    int lm = lane & 15, lk = lane >> 4;

    for (int i = tid; i < 400; i += 256)
        *(f32x4*)&sPCf[i*4] = (f32x4){0.f,0.f,0.f,0.f};
    {
        const ushort* Qp = X1 + (rowbase + w0 + lm)*128 + lk*8;
        bf16x8 aq0 = *(const bf16x8*)(Qp);
        bf16x8 aq1 = *(const bf16x8*)(Qp + 32);
        for (int xt = wv; xt < 6; xt += 4){
            int xrow = xt*16 + lm;
            int gx = bl + xrow;
            bf16x8 b0 = {0,0,0,0,0,0,0,0}, b1 = {0,0,0,0,0,0,0,0};
            if (gx >= 0 && gx < WW){
                const ushort* Kp = X1 + (rowbase + gx)*128 + 64 + lk*8;
                b0 = *(const bf16x8*)(Kp);
                b1 = *(const bf16x8*)(Kp + 32);
            }
            f32x4 acc = {0.f,0.f,0.f,0.f};
            acc = __builtin_amdgcn_mfma_f32_16x16x32_bf16(aq0, b0, acc, 0,0,0);
            acc = __builtin_amdgcn_mfma_f32_16x16x32_bf16(aq1, b1, acc, 0,0,0);
            *(f32x4*)&sS[xrow*STS2 + lk*4] = acc;
        }
    }
    __syncthreads();

    int px  = tid >> 4;
    int l16 = tid & 15;
    int w   = w0 + px;
    size_t n = rowbase + w;
    float wf = (float)w;

    float cost[2]; int xi0[2], xi1[2]; float frk[2];
    #pragma unroll
    for (int t=0; t<2; ++t){
        int d = l16*2 + t;
        float srcx = fminf(fmaxf(wf + (float)d*sf, 0.f), 191.0f);
        int x0 = (int)floorf(srcx);
        int x1 = min(x0+1, WW-1);
        float fr = srcx - (float)x0;
        int i0 = min(max(x0 - bl, 0), BANDC-1);
        int i1 = min(max(x1 - bl, 0), BANDC-1);
        xi0[t] = i0; xi1[t] = i1; frk[t] = fr;
        float s0 = sS[i0*STS2 + px];
        float s1 = sS[i1*STS2 + px];
        cost[t] = (s0 + fr*(s1-s0)) * 0.125f;
    }
    *(float2*)(C1 + n*DD + l16*2) = make_float2(cost[0], cost[1]);
    float mm = fmaxf(cost[0], cost[1]);
    mm = fmaxf(mm, __shfl_xor(mm, 1));
    mm = fmaxf(mm, __shfl_xor(mm, 2));
    mm = fmaxf(mm, __shfl_xor(mm, 4));
    mm = fmaxf(mm, __shfl_xor(mm, 8));
    float e0 = __expf(cost[0]-mm), e1 = __expf(cost[1]-mm);
    float ss = e0 + e1;
    ss += __shfl_xor(ss, 1);
    ss += __shfl_xor(ss, 2);
    ss += __shfl_xor(ss, 4);
    ss += __shfl_xor(ss, 8);
    float inv = 1.f/ss;
    float p0 = e0*inv, p1 = e1*inv;
    {
        float w1a = p0*frk[0], w0a = p0 - w1a;
        float w1b = p1*frk[1], w0b = p1 - w1b;
        atomicAdd(&sPCf[px*PFS2 + xi0[0]], w0a);
        atomicAdd(&sPCf[px*PFS2 + xi1[0]], w1a);
        atomicAdd(&sPCf[px*PFS2 + xi0[1]], w0b);
        atomicAdd(&sPCf[px*PFS2 + xi1[1]], w1b);
    }
    __syncthreads();

    {
        int mi = wv;
        int c  = mi*16 + lm;
        const ushort* Vp = VbT + (size_t)c*NPIX + rowbase + bl;
        f32x4 acc = {0.f,0.f,0.f,0.f};
        #pragma unroll
        for (int kt=0; kt<3; ++kt){
            int gx = bl + kt*32 + lk*8;
            bf16x8 av = {0,0,0,0,0,0,0,0};
            if (gx >= 0 && gx < WW) av = *(const bf16x8*)(Vp + kt*32 + lk*8);
            f32x4 v0 = *(const f32x4*)&sPCf[lm*PFS2 + kt*32 + lk*8];
            f32x4 v1 = *(const f32x4*)&sPCf[lm*PFS2 + kt*32 + lk*8 + 4];
            bf16x8 bbf;
            #pragma unroll
            for (int jj=0;jj<4;++jj){
                bbf[jj]   = (short)f2b(v0[jj]);
                bbf[jj+4] = (short)f2b(v1[jj]);
            }
            acc = __builtin_amdgcn_mfma_f32_16x16x32_bf16(av, bbf, acc, 0,0,0);
        }
        uint u0 = (uint)f2b(acc[0]) | ((uint)f2b(acc[1])<<16);
        uint u1 = (uint)f2b(acc[2]) | ((uint)f2b(acc[3])<<16);
        *(uint2*)(Agg + (rowbase + w0 + lm)*64 + mi*16 + lk*4) = make_uint2(u0, u1);
    }
}

// ---------- G2: conv3x3 p1, LDS-staged implicit GEMM, ELU ----------
__global__ __launch_bounds__(256) void g_conv1(
    const ushort* __restrict__ X1, const ushort* __restrict__ Agg,
    const ushort* __restrict__ A1, const float* __restrict__ p1b,
    ushort* __restrict__ X2)
{
    __shared__ ushort sB[3*16*34*8];
    int tid = threadIdx.x;
    int wv = tid >> 6, lane = tid & 63;
    int lm = lane & 15, lk = lane >> 4;
    int bid = blockIdx.x;
    int tile = (bid & 7)*96 + (bid >> 3);
    int n0 = tile * 32;
    int b  = n0 / HW;
    int pl = n0 % HW;
    int h  = pl / WW, w0 = pl % WW;

    for (int i = tid; i < 1632; i += 256){
        int dh = i / 544, rem2 = i % 544;
        int c16 = rem2 / 34, x = rem2 % 34;
        int hh = h + dh - 1, wx = w0 + x - 1;
        uint4 val = make_uint4(0,0,0,0);
        if (hh >= 0 && hh < HH && wx >= 0 && wx < WW){
            size_t pix = (size_t)b*HW + (size_t)hh*WW + wx;
            val = (c16 < 8) ? *(const uint4*)(X1 + pix*128 + c16*8)
                            : *(const uint4*)(Agg + pix*64 + (c16-8)*8);
        }
        *(uint4*)&sB[((dh*16 + c16)*34 + x)*8] = val;
    }
    __syncthreads();

    int mw = wv & 1, nw = wv >> 1;
    const ushort* Ap = A1 + (size_t)(mw*32 + lm)*1152 + lk*8;
    f32x4 acc0 = {0.f,0.f,0.f,0.f}, acc1 = {0.f,0.f,0.f,0.f};
    int xb = nw*16 + lm;
    #pragma unroll
    for (int t=0; t<9; ++t){
        int dh = t/3, dw = t%3;
        #pragma unroll
        for (int c0=0; c0<128; c0+=32){
            bf16x8 bb = *(const bf16x8*)&sB[((dh*16 + (c0>>3)+lk)*34 + xb + dw)*8];
            bf16x8 a0 = *(const bf16x8*)(Ap + t*128 + c0);
            bf16x8 a1 = *(const bf16x8*)(Ap + (size_t)16*1152 + t*128 + c0);
            acc0 = __builtin_amdgcn_mfma_f32_16x16x32_bf16(a0, bb, acc0, 0,0,0);
            acc1 = __builtin_amdgcn_mfma_f32_16x16x32_bf16(a1, bb, acc1, 0,0,0);
        }
    }
    int pg = n0 + nw*16 + lm;
    int o0 = mw*32 + lk*4;
    {
        uint u0 = (uint)f2b(eluf(acc0[0]+p1b[o0]))   | ((uint)f2b(eluf(acc0[1]+p1b[o0+1]))<<16);
        uint u1 = (uint)f2b(eluf(acc0[2]+p1b[o0+2])) | ((uint)f2b(eluf(acc0[3]+p1b[o0+3]))<<16);
        *(uint2*)(X2 + (size_t)pg*64 + o0) = make_uint2(u0, u1);
        int o1 = o0 + 16;
        uint u2 = (uint)f2b(eluf(acc1[0]+p1b[o1]))   | ((uint)f2b(eluf(acc1[1]+p1b[o1+1]))<<16);
        uint u3 = (uint)f2b(eluf(acc1[2]+p1b[o1+2])) | ((uint)f2b(eluf(acc1[3]+p1b[o1+3]))<<16);
        *(uint2*)(X2 + (size_t)pg*64 + o1) = make_uint2(u2, u3);
    }
}

// ---------- G3+G4 fused: conv p2 + residual -> cost_out, softmax -> NC(LDS),
//            final conv1x1 (Ar on-the-fly from rw) -> xout ----------
__global__ __launch_bounds__(256) void g_conv2final(
    const ushort* __restrict__ X2, const ushort* __restrict__ A2,
    const float* __restrict__ p2b, const float* __restrict__ C1,
    const float* __restrict__ t_feat, const float* __restrict__ rw,
    const float* __restrict__ rb,
    float* __restrict__ cost_out, float* __restrict__ xout)
{
    __shared__ ushort sT[32*264];
    __shared__ float  sO[32*36];
    __shared__ ushort sN[32*40];
    ushort* sB = sT;
    int tid = threadIdx.x;
    int wv = tid >> 6, lane = tid & 63;
    int lm = lane & 15, lk = lane >> 4;
    int bid = blockIdx.x;
    int tile = (bid & 7)*96 + (bid >> 3);
    int n0 = tile * 32;
    int b  = n0 / HW;
    int pl = n0 % HW;
    int h  = pl / WW, w0 = pl % WW;

    for (int i = tid; i < 816; i += 256){
        int dh = i / 272, rem2 = i % 272;
        int c16 = rem2 / 34, x = rem2 % 34;
        int hh = h + dh - 1, wx = w0 + x - 1;
        uint4 val = make_uint4(0,0,0,0);
        if (hh >= 0 && hh < HH && wx >= 0 && wx < WW)
            val = *(const uint4*)(X2 + ((size_t)b*HW + (size_t)hh*WW + wx)*64 + c16*8);
        *(uint4*)&sB[((dh*8 + c16)*34 + x)*8] = val;
    }
    __syncthreads();

    {
        int mw = wv & 1, nw = wv >> 1;
        const ushort* Ap = A2 + (size_t)(mw*16 + lm)*576 + lk*8;
        f32x4 acc = {0.f,0.f,0.f,0.f};
        int xb = nw*16 + lm;
        #pragma unroll
        for (int t=0; t<9; ++t){
            int dh = t/3, dw = t%3;
            #pragma unroll
            for (int c0=0; c0<64; c0+=32){
                bf16x8 bb = *(const bf16x8*)&sB[((dh*8 + (c0>>3)+lk)*34 + xb + dw)*8];
                bf16x8 aw = *(const bf16x8*)(Ap + t*64 + c0);
                acc = __builtin_amdgcn_mfma_f32_16x16x32_bf16(aw, bb, acc, 0,0,0);
            }
        }
        int pg = n0 + nw*16 + lm;
        int pll = pg % HW;
        int o = mw*16 + lk*4;
        f32x4 cv = *(const f32x4*)(C1 + (size_t)pg*DD + o);
        f32x4 outv;
        #pragma unroll
        for (int j=0;j<4;++j){
            outv[j] = (cv[j] + acc[j] + p2b[o+j]) * 0.5f;
            cost_out[((size_t)(b*DD + o + j))*HW + pll] = outv[j];
        }
        *(f32x4*)&sO[(nw*16 + lm)*36 + o] = outv;
    }
    __syncthreads();

    {
        int px = tid >> 3;
        int g  = tid & 7;
        f32x4 v = *(const f32x4*)&sO[px*36 + g*4];
        float m = fmaxf(fmaxf(v[0],v[1]), fmaxf(v[2],v[3]));
        m = fmaxf(m, __shfl_xor(m, 1));
        m = fmaxf(m, __shfl_xor(m, 2));
        m = fmaxf(m, __shfl_xor(m, 4));
        float e[4]; float s = 0.f;
        #pragma unroll
        for (int j=0;j<4;++j){ e[j] = __expf(v[j]-m); s += e[j]; }
        s += __shfl_xor(s, 1);
        s += __shfl_xor(s, 2);
        s += __shfl_xor(s, 4);
        float invs = 1.f/s;
        uint u0 = (uint)f2b(e[0]*invs) | ((uint)f2b(e[1]*invs)<<16);
        uint u1 = (uint)f2b(e[2]*invs) | ((uint)f2b(e[3]*invs)<<16);
        *(uint2*)&sN[px*40 + g*4] = make_uint2(u0, u1);
    }
    for (int i = tid; i < 1024; i += 256){
        int px = i & 31, c8 = i >> 5;
        const float* pt = t_feat + ((size_t)(b*CC + c8*8))*HW + pl + px;
        uint u[4];
        #pragma unroll
        for (int j2=0;j2<4;++j2)
            u[j2] = (uint)f2b(pt[(size_t)(2*j2)*HW]) | ((uint)f2b(pt[(size_t)(2*j2+1)*HW])<<16);
        uint4 q4; q4.x=u[0]; q4.y=u[1]; q4.z=u[2]; q4.w=u[3];
        *(uint4*)&sT[(px*33 + c8)*8] = q4;
    }
    __syncthreads();

    {
        f32x4 acc[4][2];
        #pragma unroll
        for (int mi=0;mi<4;++mi){ acc[mi][0]=(f32x4){0.f,0.f,0.f,0.f}; acc[mi][1]=(f32x4){0.f,0.f,0.f,0.f}; }
        const float* Ap = rw + (size_t)(wv*64 + lm)*288 + lk*8;

        #pragma unroll
        for (int k0=0; k0<288; k0+=32){
            bf16x8 aw[4];
            #pragma unroll
            for (int mi=0;mi<4;++mi) aw[mi] = ldw8(Ap + (size_t)mi*16*288 + k0);
            #pragma unroll
            for (int nt=0; nt<2; ++nt){
                int prow = nt*16 + lm;
                bf16x8 bb = (k0 < 256) ? *(const bf16x8*)&sT[(prow*33 + (k0>>3) + lk)*8]
                                       : *(const bf16x8*)&sN[(prow*5 + lk)*8];
                #pragma unroll
                for (int mi=0;mi<4;++mi)
                    acc[mi][nt] = __builtin_amdgcn_mfma_f32_16x16x32_bf16(aw[mi], bb, acc[mi][nt], 0,0,0);
            }
        }
        #pragma unroll
        for (int mi=0;mi<4;++mi){
            int o = wv*64 + mi*16 + lk*4;
            #pragma unroll
            for (int nt=0; nt<2; ++nt){
                int p = n0 + nt*16 + lm;
                int bb2 = p / HW, pl2 = p % HW;
                #pragma unroll
                for (int j=0;j<4;++j)
                    xout[((size_t)(bb2*CC + o + j))*HW + pl2] = eluf(acc[mi][nt][j] + rb[o+j]);
            }
        }
    }
}

extern "C" void kernel_launch(void* const* d_in, const int* in_sizes, int n_in,
                              void* d_out, int out_size, void* d_ws, size_t ws_size,
                              hipStream_t stream)
{
    const float* t_feat = (const float*)d_in[0];
    const float* s_feat = (const float*)d_in[1];
    const float* directs= (const float*)d_in[2];
    const float* qw = (const float*)d_in[3];
    const float* qb = (const float*)d_in[4];
    const float* kw = (const float*)d_in[5];
    const float* kb = (const float*)d_in[6];
    const float* vw = (const float*)d_in[7];
    const float* vb = (const float*)d_in[8];
    const float* p1w= (const float*)d_in[9];
    const float* p1b= (const float*)d_in[10];
    const float* p2w= (const float*)d_in[11];
    const float* p2b= (const float*)d_in[12];
    const float* rw = (const float*)d_in[13];
    const float* rb = (const float*)d_in[14];
    const int* img_w= (const int*)d_in[15];

    char* wsb = (char*)d_ws;
    char*  tsreg = wsb + 12582912;
    ushort* X2   = (ushort*)tsreg;
    float*  C1   = (float*)(tsreg + 3145728);
    ushort* Agg  = (ushort*)(tsreg + 6291456);
    ushort* X1   = (ushort*)(wsb + 25165824);    // [NPIX][128] bf16 (q | K)
    ushort* VbT  = (ushort*)(wsb + 31457280);    // [64][NPIX] bf16 (V transposed)
    ushort* A1   = (ushort*)(wsb + 34702336);
    ushort* A2   = (ushort*)(wsb + 34849792);
    if (ws_size < 35034112) return;

    float* xout     = (float*)d_out;                 // [B,256,H,W] f32
    float* cost_out = xout + (size_t)BB*CC*HW;       // [B,32,H,W] f32

    g_qkv       <<<768,  256, 0, stream>>>(t_feat, s_feat, qw,qb,kw,kb,vw,vb,
                                           p1w, p2w, A1, A2, X1, VbT);
    k_ca        <<<1536, 256, 0, stream>>>(X1, VbT, directs, img_w, C1, Agg);
    g_conv1     <<<768,  256, 0, stream>>>(X1, Agg, A1, p1b, X2);
    g_conv2final<<<768,  256, 0, stream>>>(X2, A2, p2b, C1, t_feat, rw, rb,
                                           cost_out, xout);
}

// Round 17
// 95.427 us; speedup vs baseline: 4.1952x; 1.2017x over previous
//
#include <hip/hip_runtime.h>

#define BB 2
#define CC 256
#define CQ 64
#define DD 32
#define HH 64
#define WW 192
#define HW (HH*WW)     // 12288
#define NPIX (BB*HW)   // 24576

typedef __attribute__((ext_vector_type(8))) short bf16x8;
typedef __attribute__((ext_vector_type(4))) float f32x4;

__device__ __forceinline__ float b2f(ushort s){ return __uint_as_float(((uint)s)<<16); }
__device__ __forceinline__ ushort f2b(float f){
    uint u = __float_as_uint(f);
    return (ushort)((u + 0x7fffu + ((u>>16)&1u)) >> 16);
}
__device__ __forceinline__ float eluf(float v){ return v > 0.f ? v : (__expf(v)-1.f); }

// ---------- prep: weights only -> bf16 GEMM-A layouts ----------
__global__ __launch_bounds__(256) void k_prep_w(
    const float* __restrict__ qw, const float* __restrict__ qb,
    const float* __restrict__ kw, const float* __restrict__ kb,
    const float* __restrict__ vw, const float* __restrict__ vb,
    const float* __restrict__ p1w, const float* __restrict__ p2w,
    const float* __restrict__ rw,
    ushort* __restrict__ Wqkv, float* __restrict__ bqkv,
    ushort* __restrict__ A1, ushort* __restrict__ A2, ushort* __restrict__ Ar)
{
    int id = blockIdx.x*256 + threadIdx.x;
    if (id < 49152) {
        int o = id / 256, c = id % 256;
        float v = (o<64)? qw[o*256+c] : (o<128)? kw[(o-64)*256+c] : vw[(o-128)*256+c];
        Wqkv[id] = f2b(v);
    } else if (id < 49344) {
        int o = id - 49152;
        bqkv[o] = (o<64)? qb[o] : (o<128)? kb[o-64] : vb[o-128];
    } else if (id < 49344+73728) {
        int i = id - 49344;
        int o = i/1152, r = i%1152, t = r/128, ci = r%128;
        A1[i] = f2b(p1w[(size_t)(o*128+ci)*9 + t]);
    } else if (id < 49344+73728+18432) {
        int i = id - (49344+73728);
        int o = i/576, r = i%576, t = r/64, ci = r%64;
        A2[i] = f2b(p2w[(size_t)(o*64+ci)*9 + t]);
    } else if (id < 49344+73728+18432+73728) {
        int i = id - (49344+73728+18432);
        Ar[i] = f2b(rw[i]);
    }
}

// ---------- G1: qkv conv1x1; stages DIRECTLY from NCHW f32 ----------
__global__ __launch_bounds__(256) void g_qkv(
    const float* __restrict__ t_feat, const float* __restrict__ s_feat,
    const ushort* __restrict__ Wqkv, const float* __restrict__ bqkv,
    ushort* __restrict__ X1, ushort* __restrict__ VbT)
{
    __shared__ ushort sT[32*264];
    __shared__ ushort sS[32*264];
    int tid = threadIdx.x;
    int bid = blockIdx.x;
    int tile = (bid & 7)*96 + (bid >> 3);
    int p0 = tile * 32;
    int b0  = p0 / HW;
    int pl0 = p0 % HW;

    for (int i = tid; i < 1024; i += 256){
        int px = i & 31, c8 = i >> 5;
        const float* pt = t_feat + ((size_t)(b0*CC + c8*8))*HW + pl0 + px;
        const float* ps = s_feat + ((size_t)(b0*CC + c8*8))*HW + pl0 + px;
        uint ut[4], us[4];
        #pragma unroll
        for (int j2=0;j2<4;++j2){
            ut[j2] = (uint)f2b(pt[(size_t)(2*j2)*HW]) | ((uint)f2b(pt[(size_t)(2*j2+1)*HW])<<16);
            us[j2] = (uint)f2b(ps[(size_t)(2*j2)*HW]) | ((uint)f2b(ps[(size_t)(2*j2+1)*HW])<<16);
        }
        uint4 qt; qt.x=ut[0]; qt.y=ut[1]; qt.z=ut[2]; qt.w=ut[3];
        uint4 qs; qs.x=us[0]; qs.y=us[1]; qs.z=us[2]; qs.w=us[3];
        *(uint4*)&sT[(px*33 + c8)*8] = qt;
        *(uint4*)&sS[(px*33 + c8)*8] = qs;
    }
    __syncthreads();

    int wv = tid >> 6, lane = tid & 63;
    int lm = lane & 15, lk = lane >> 4;
    f32x4 acc[3][2];
    #pragma unroll
    for (int g=0;g<3;++g){ acc[g][0]=(f32x4){0.f,0.f,0.f,0.f}; acc[g][1]=(f32x4){0.f,0.f,0.f,0.f}; }
    const ushort* Ap = Wqkv + (size_t)(wv*16 + lm)*CC + lk*8;

    #pragma unroll
    for (int k0=0; k0<CC; k0+=32){
        bf16x8 a0 = *(const bf16x8*)(Ap + k0);
        bf16x8 a1 = *(const bf16x8*)(Ap + 64*CC + k0);
        bf16x8 a2 = *(const bf16x8*)(Ap + 128*CC + k0);
        #pragma unroll
        for (int nt=0; nt<2; ++nt){
            int ch = (nt*16+lm)*33 + (k0>>3) + lk;
            bf16x8 bT = *(const bf16x8*)&sT[ch*8];
            bf16x8 bS = *(const bf16x8*)&sS[ch*8];
            acc[0][nt] = __builtin_amdgcn_mfma_f32_16x16x32_bf16(a0, bT, acc[0][nt], 0,0,0);
            acc[1][nt] = __builtin_amdgcn_mfma_f32_16x16x32_bf16(a1, bS, acc[1][nt], 0,0,0);
            acc[2][nt] = __builtin_amdgcn_mfma_f32_16x16x32_bf16(a2, bS, acc[2][nt], 0,0,0);
        }
    }
    int ol = wv*16 + lk*4;
    #pragma unroll
    for (int nt=0; nt<2; ++nt){
        int p = p0 + nt*16 + lm;
        {
            uint u0 = (uint)f2b(acc[0][nt][0]+bqkv[ol])   | ((uint)f2b(acc[0][nt][1]+bqkv[ol+1])<<16);
            uint u1 = (uint)f2b(acc[0][nt][2]+bqkv[ol+2]) | ((uint)f2b(acc[0][nt][3]+bqkv[ol+3])<<16);
            *(uint2*)(X1 + (size_t)p*128 + ol) = make_uint2(u0, u1);
        }
        {
            int ob = 64 + ol;
            uint u0 = (uint)f2b(acc[1][nt][0]+bqkv[ob])   | ((uint)f2b(acc[1][nt][1]+bqkv[ob+1])<<16);
            uint u1 = (uint)f2b(acc[1][nt][2]+bqkv[ob+2]) | ((uint)f2b(acc[1][nt][3]+bqkv[ob+3])<<16);
            *(uint2*)(X1 + (size_t)p*128 + 64 + ol) = make_uint2(u0, u1);
        }
        #pragma unroll
        for (int j=0;j<4;++j)
            VbT[(size_t)(ol+j)*NPIX + p] = f2b(acc[2][nt][j] + bqkv[128 + ol + j]);
    }
}

// ---------- k_ca: MFMA-banded, 2-barrier, 16px/block, 256 thr ----------
#define BANDC 96
#define STS2 20
#define PFS2 100
__global__ __launch_bounds__(256) void k_ca(
    const ushort* __restrict__ X1, const ushort* __restrict__ VbT,
    const float* __restrict__ directs, const int* __restrict__ img_w_p,
    float* __restrict__ C1, ushort* __restrict__ Agg)
{
    __shared__ float sS[BANDC*STS2];
    __shared__ float sPCf[16*PFS2];
    int tid = threadIdx.x;
    int j   = blockIdx.x;
    int r8  = j & 7;
    int kk  = j >> 3;
    int sub = kk % 12;
    int rhi = kk / 12;
    int row = rhi*8 + r8;
    int b   = row >> 6;
    int h   = row & 63;
    int w0  = sub * 16;
    size_t rowbase = (size_t)b*HW + (size_t)h*WW;

    int imw = img_w_p[0];
    float rel = (imw != 640) ? (640.0f/(float)imw) : 1.0f;
    float sf = 0.01f * rel * directs[b] * 191.0f;
    int bl = (sf < 0.f) ? (w0 - 64) : w0;

    int wv = tid >> 6, lane = tid & 63;
    int lm = lane & 15, lk = lane >> 4;

    for (int i = tid; i < 400; i += 256)
        *(f32x4*)&sPCf[i*4] = (f32x4){0.f,0.f,0.f,0.f};
    {
        const ushort* Qp = X1 + (rowbase + w0 + lm)*128 + lk*8;
        bf16x8 aq0 = *(const bf16x8*)(Qp);
        bf16x8 aq1 = *(const bf16x8*)(Qp + 32);
        for (int xt = wv; xt < 6; xt += 4){
            int xrow = xt*16 + lm;
            int gx = bl + xrow;
            bf16x8 b0 = {0,0,0,0,0,0,0,0}, b1 = {0,0,0,0,0,0,0,0};
            if (gx >= 0 && gx < WW){
                const ushort* Kp = X1 + (rowbase + gx)*128 + 64 + lk*8;
                b0 = *(const bf16x8*)(Kp);
                b1 = *(const bf16x8*)(Kp + 32);
            }
            f32x4 acc = {0.f,0.f,0.f,0.f};
            acc = __builtin_amdgcn_mfma_f32_16x16x32_bf16(aq0, b0, acc, 0,0,0);
            acc = __builtin_amdgcn_mfma_f32_16x16x32_bf16(aq1, b1, acc, 0,0,0);
            *(f32x4*)&sS[xrow*STS2 + lk*4] = acc;
        }
    }
    __syncthreads();

    int px  = tid >> 4;
    int l16 = tid & 15;
    int w   = w0 + px;
    size_t n = rowbase + w;
    float wf = (float)w;

    float cost[2]; int xi0[2], xi1[2]; float frk[2];
    #pragma unroll
    for (int t=0; t<2; ++t){
        int d = l16*2 + t;
        float srcx = fminf(fmaxf(wf + (float)d*sf, 0.f), 191.0f);
        int x0 = (int)floorf(srcx);
        int x1 = min(x0+1, WW-1);
        float fr = srcx - (float)x0;
        int i0 = min(max(x0 - bl, 0), BANDC-1);
        int i1 = min(max(x1 - bl, 0), BANDC-1);
        xi0[t] = i0; xi1[t] = i1; frk[t] = fr;
        float s0 = sS[i0*STS2 + px];
        float s1 = sS[i1*STS2 + px];
        cost[t] = (s0 + fr*(s1-s0)) * 0.125f;
    }
    *(float2*)(C1 + n*DD + l16*2) = make_float2(cost[0], cost[1]);
    float mm = fmaxf(cost[0], cost[1]);
    mm = fmaxf(mm, __shfl_xor(mm, 1));
    mm = fmaxf(mm, __shfl_xor(mm, 2));
    mm = fmaxf(mm, __shfl_xor(mm, 4));
    mm = fmaxf(mm, __shfl_xor(mm, 8));
    float e0 = __expf(cost[0]-mm), e1 = __expf(cost[1]-mm);
    float ss = e0 + e1;
    ss += __shfl_xor(ss, 1);
    ss += __shfl_xor(ss, 2);
    ss += __shfl_xor(ss, 4);
    ss += __shfl_xor(ss, 8);
    float inv = 1.f/ss;
    float p0 = e0*inv, p1 = e1*inv;
    {
        float w1a = p0*frk[0], w0a = p0 - w1a;
        float w1b = p1*frk[1], w0b = p1 - w1b;
        atomicAdd(&sPCf[px*PFS2 + xi0[0]], w0a);
        atomicAdd(&sPCf[px*PFS2 + xi1[0]], w1a);
        atomicAdd(&sPCf[px*PFS2 + xi0[1]], w0b);
        atomicAdd(&sPCf[px*PFS2 + xi1[1]], w1b);
    }
    __syncthreads();

    {
        int mi = wv;
        int c  = mi*16 + lm;
        const ushort* Vp = VbT + (size_t)c*NPIX + rowbase + bl;
        f32x4 acc = {0.f,0.f,0.f,0.f};
        #pragma unroll
        for (int kt=0; kt<3; ++kt){
            int gx = bl + kt*32 + lk*8;
            bf16x8 av = {0,0,0,0,0,0,0,0};
            if (gx >= 0 && gx < WW) av = *(const bf16x8*)(Vp + kt*32 + lk*8);
            f32x4 v0 = *(const f32x4*)&sPCf[lm*PFS2 + kt*32 + lk*8];
            f32x4 v1 = *(const f32x4*)&sPCf[lm*PFS2 + kt*32 + lk*8 + 4];
            bf16x8 bbf;
            #pragma unroll
            for (int jj=0;jj<4;++jj){
                bbf[jj]   = (short)f2b(v0[jj]);
                bbf[jj+4] = (short)f2b(v1[jj]);
            }
            acc = __builtin_amdgcn_mfma_f32_16x16x32_bf16(av, bbf, acc, 0,0,0);
        }
        uint u0 = (uint)f2b(acc[0]) | ((uint)f2b(acc[1])<<16);
        uint u1 = (uint)f2b(acc[2]) | ((uint)f2b(acc[3])<<16);
        *(uint2*)(Agg + (rowbase + w0 + lm)*64 + mi*16 + lk*4) = make_uint2(u0, u1);
    }
}

// ---------- G2: conv3x3 p1, LDS-staged implicit GEMM, ELU ----------
__global__ __launch_bounds__(256) void g_conv1(
    const ushort* __restrict__ X1, const ushort* __restrict__ Agg,
    const ushort* __restrict__ A1, const float* __restrict__ p1b,
    ushort* __restrict__ X2)
{
    __shared__ ushort sB[3*16*34*8];
    int tid = threadIdx.x;
    int wv = tid >> 6, lane = tid & 63;
    int lm = lane & 15, lk = lane >> 4;
    int bid = blockIdx.x;
    int tile = (bid & 7)*96 + (bid >> 3);
    int n0 = tile * 32;
    int b  = n0 / HW;
    int pl = n0 % HW;
    int h  = pl / WW, w0 = pl % WW;

    for (int i = tid; i < 1632; i += 256){
        int dh = i / 544, rem2 = i % 544;
        int c16 = rem2 / 34, x = rem2 % 34;
        int hh = h + dh - 1, wx = w0 + x - 1;
        uint4 val = make_uint4(0,0,0,0);
        if (hh >= 0 && hh < HH && wx >= 0 && wx < WW){
            size_t pix = (size_t)b*HW + (size_t)hh*WW + wx;
            val = (c16 < 8) ? *(const uint4*)(X1 + pix*128 + c16*8)
                            : *(const uint4*)(Agg + pix*64 + (c16-8)*8);
        }
        *(uint4*)&sB[((dh*16 + c16)*34 + x)*8] = val;
    }
    __syncthreads();

    int mw = wv & 1, nw = wv >> 1;
    const ushort* Ap = A1 + (size_t)(mw*32 + lm)*1152 + lk*8;
    f32x4 acc0 = {0.f,0.f,0.f,0.f}, acc1 = {0.f,0.f,0.f,0.f};
    int xb = nw*16 + lm;
    #pragma unroll
    for (int t=0; t<9; ++t){
        int dh = t/3, dw = t%3;
        #pragma unroll
        for (int c0=0; c0<128; c0+=32){
            bf16x8 bb = *(const bf16x8*)&sB[((dh*16 + (c0>>3)+lk)*34 + xb + dw)*8];
            bf16x8 a0 = *(const bf16x8*)(Ap + t*128 + c0);
            bf16x8 a1 = *(const bf16x8*)(Ap + (size_t)16*1152 + t*128 + c0);
            acc0 = __builtin_amdgcn_mfma_f32_16x16x32_bf16(a0, bb, acc0, 0,0,0);
            acc1 = __builtin_amdgcn_mfma_f32_16x16x32_bf16(a1, bb, acc1, 0,0,0);
        }
    }
    int pg = n0 + nw*16 + lm;
    int o0 = mw*32 + lk*4;
    {
        uint u0 = (uint)f2b(eluf(acc0[0]+p1b[o0]))   | ((uint)f2b(eluf(acc0[1]+p1b[o0+1]))<<16);
        uint u1 = (uint)f2b(eluf(acc0[2]+p1b[o0+2])) | ((uint)f2b(eluf(acc0[3]+p1b[o0+3]))<<16);
        *(uint2*)(X2 + (size_t)pg*64 + o0) = make_uint2(u0, u1);
        int o1 = o0 + 16;
        uint u2 = (uint)f2b(eluf(acc1[0]+p1b[o1]))   | ((uint)f2b(eluf(acc1[1]+p1b[o1+1]))<<16);
        uint u3 = (uint)f2b(eluf(acc1[2]+p1b[o1+2])) | ((uint)f2b(eluf(acc1[3]+p1b[o1+3]))<<16);
        *(uint2*)(X2 + (size_t)pg*64 + o1) = make_uint2(u2, u3);
    }
}

// ---------- G3+G4 fused: conv p2 + residual -> cost_out, softmax -> NC(LDS),
//            final conv1x1 on concat(t_feat, NC) -> xout ----------
__global__ __launch_bounds__(256) void g_conv2final(
    const ushort* __restrict__ X2, const ushort* __restrict__ A2,
    const float* __restrict__ p2b, const float* __restrict__ C1,
    const float* __restrict__ t_feat, const ushort* __restrict__ Ar,
    const float* __restrict__ rb,
    float* __restrict__ cost_out, float* __restrict__ xout)
{
    __shared__ ushort sT[32*264];
    __shared__ float  sO[32*36];
    __shared__ ushort sN[32*40];
    ushort* sB = sT;
    int tid = threadIdx.x;
    int wv = tid >> 6, lane = tid & 63;
    int lm = lane & 15, lk = lane >> 4;
    int bid = blockIdx.x;
    int tile = (bid & 7)*96 + (bid >> 3);
    int n0 = tile * 32;
    int b  = n0 / HW;
    int pl = n0 % HW;
    int h  = pl / WW, w0 = pl % WW;

    for (int i = tid; i < 816; i += 256){
        int dh = i / 272, rem2 = i % 272;
        int c16 = rem2 / 34, x = rem2 % 34;
        int hh = h + dh - 1, wx = w0 + x - 1;
        uint4 val = make_uint4(0,0,0,0);
        if (hh >= 0 && hh < HH && wx >= 0 && wx < WW)
            val = *(const uint4*)(X2 + ((size_t)b*HW + (size_t)hh*WW + wx)*64 + c16*8);
        *(uint4*)&sB[((dh*8 + c16)*34 + x)*8] = val;
    }
    __syncthreads();

    {
        int mw = wv & 1, nw = wv >> 1;
        const ushort* Ap = A2 + (size_t)(mw*16 + lm)*576 + lk*8;
        f32x4 acc = {0.f,0.f,0.f,0.f};
        int xb = nw*16 + lm;
        #pragma unroll
        for (int t=0; t<9; ++t){
            int dh = t/3, dw = t%3;
            #pragma unroll
            for (int c0=0; c0<64; c0+=32){
                bf16x8 bb = *(const bf16x8*)&sB[((dh*8 + (c0>>3)+lk)*34 + xb + dw)*8];
                bf16x8 aw = *(const bf16x8*)(Ap + t*64 + c0);
                acc = __builtin_amdgcn_mfma_f32_16x16x32_bf16(aw, bb, acc, 0,0,0);
            }
        }
        int pg = n0 + nw*16 + lm;
        int pll = pg % HW;
        int o = mw*16 + lk*4;
        f32x4 cv = *(const f32x4*)(C1 + (size_t)pg*DD + o);
        f32x4 outv;
        #pragma unroll
        for (int j=0;j<4;++j){
            outv[j] = (cv[j] + acc[j] + p2b[o+j]) * 0.5f;
            cost_out[((size_t)(b*DD + o + j))*HW + pll] = outv[j];
        }
        *(f32x4*)&sO[(nw*16 + lm)*36 + o] = outv;
    }
    __syncthreads();

    {
        int px = tid >> 3;
        int g  = tid & 7;
        f32x4 v = *(const f32x4*)&sO[px*36 + g*4];
        float m = fmaxf(fmaxf(v[0],v[1]), fmaxf(v[2],v[3]));
        m = fmaxf(m, __shfl_xor(m, 1));
        m = fmaxf(m, __shfl_xor(m, 2));
        m = fmaxf(m, __shfl_xor(m, 4));
        float e[4]; float s = 0.f;
        #pragma unroll
        for (int j=0;j<4;++j){ e[j] = __expf(v[j]-m); s += e[j]; }
        s += __shfl_xor(s, 1);
        s += __shfl_xor(s, 2);
        s += __shfl_xor(s, 4);
        float invs = 1.f/s;
        uint u0 = (uint)f2b(e[0]*invs) | ((uint)f2b(e[1]*invs)<<16);
        uint u1 = (uint)f2b(e[2]*invs) | ((uint)f2b(e[3]*invs)<<16);
        *(uint2*)&sN[px*40 + g*4] = make_uint2(u0, u1);
    }
    for (int i = tid; i < 1024; i += 256){
        int px = i & 31, c8 = i >> 5;
        const float* pt = t_feat + ((size_t)(b*CC + c8*8))*HW + pl + px;
        uint u[4];
        #pragma unroll
        for (int j2=0;j2<4;++j2)
            u[j2] = (uint)f2b(pt[(size_t)(2*j2)*HW]) | ((uint)f2b(pt[(size_t)(2*j2+1)*HW])<<16);
        uint4 q4; q4.x=u[0]; q4.y=u[1]; q4.z=u[2]; q4.w=u[3];
        *(uint4*)&sT[(px*33 + c8)*8] = q4;
    }
    __syncthreads();

    {
        f32x4 acc[4][2];
        #pragma unroll
        for (int mi=0;mi<4;++mi){ acc[mi][0]=(f32x4){0.f,0.f,0.f,0.f}; acc[mi][1]=(f32x4){0.f,0.f,0.f,0.f}; }
        const ushort* Ap = Ar + (size_t)(wv*64 + lm)*288 + lk*8;

        #pragma unroll
        for (int k0=0; k0<288; k0+=32){
            bf16x8 aw[4];
            #pragma unroll
            for (int mi=0;mi<4;++mi) aw[mi] = *(const bf16x8*)(Ap + (size_t)mi*16*288 + k0);
            #pragma unroll
            for (int nt=0; nt<2; ++nt){
                int prow = nt*16 + lm;
                bf16x8 bb = (k0 < 256) ? *(const bf16x8*)&sT[(prow*33 + (k0>>3) + lk)*8]
                                       : *(const bf16x8*)&sN[(prow*5 + lk)*8];
                #pragma unroll
                for (int mi=0;mi<4;++mi)
                    acc[mi][nt] = __builtin_amdgcn_mfma_f32_16x16x32_bf16(aw[mi], bb, acc[mi][nt], 0,0,0);
            }
        }
        #pragma unroll
        for (int mi=0;mi<4;++mi){
            int o = wv*64 + mi*16 + lk*4;
            #pragma unroll
            for (int nt=0; nt<2; ++nt){
                int p = n0 + nt*16 + lm;
                int bb2 = p / HW, pl2 = p % HW;
                #pragma unroll
                for (int j=0;j<4;++j)
                    xout[((size_t)(bb2*CC + o + j))*HW + pl2] = eluf(acc[mi][nt][j] + rb[o+j]);
            }
        }
    }
}

extern "C" void kernel_launch(void* const* d_in, const int* in_sizes, int n_in,
                              void* d_out, int out_size, void* d_ws, size_t ws_size,
                              hipStream_t stream)
{
    const float* t_feat = (const float*)d_in[0];
    const float* s_feat = (const float*)d_in[1];
    const float* directs= (const float*)d_in[2];
    const float* qw = (const float*)d_in[3];
    const float* qb = (const float*)d_in[4];
    const float* kw = (const float*)d_in[5];
    const float* kb = (const float*)d_in[6];
    const float* vw = (const float*)d_in[7];
    const float* vb = (const float*)d_in[8];
    const float* p1w= (const float*)d_in[9];
    const float* p1b= (const float*)d_in[10];
    const float* p2w= (const float*)d_in[11];
    const float* p2b= (const float*)d_in[12];
    const float* rw = (const float*)d_in[13];
    const float* rb = (const float*)d_in[14];
    const int* img_w= (const int*)d_in[15];

    char* wsb = (char*)d_ws;
    char*  tsreg = wsb + 12582912;
    ushort* X2   = (ushort*)tsreg;
    float*  C1   = (float*)(tsreg + 3145728);
    ushort* Agg  = (ushort*)(tsreg + 6291456);
    ushort* X1   = (ushort*)(wsb + 25165824);    // [NPIX][128] bf16 (q | K)
    ushort* VbT  = (ushort*)(wsb + 31457280);    // [64][NPIX] bf16 (V transposed)
    ushort* Wqkv = (ushort*)(wsb + 34603008);
    float*  bqkv = (float*) (wsb + 34701312);
    ushort* A1   = (ushort*)(wsb + 34702336);
    ushort* A2   = (ushort*)(wsb + 34849792);
    ushort* Ar   = (ushort*)(wsb + 34886656);    // -> end 35,034,112
    if (ws_size < 35034112) return;

    float* xout     = (float*)d_out;                 // [B,256,H,W] f32
    float* cost_out = xout + (size_t)BB*CC*HW;       // [B,32,H,W] f32

    k_prep_w    <<<841,  256, 0, stream>>>(qw,qb,kw,kb,vw,vb,p1w,p2w,rw,
                                           Wqkv,bqkv,A1,A2,Ar);
    g_qkv       <<<768,  256, 0, stream>>>(t_feat, s_feat, Wqkv, bqkv, X1, VbT);
    k_ca        <<<1536, 256, 0, stream>>>(X1, VbT, directs, img_w, C1, Agg);
    g_conv1     <<<768,  256, 0, stream>>>(X1, Agg, A1, p1b, X2);
    g_conv2final<<<768,  256, 0, stream>>>(X2, A2, p2b, C1, t_feat, Ar, rb,
                                           cost_out, xout);
}